// Round 5
// baseline (349.350 us; speedup 1.0000x reference)
//
#include <hip/hip_runtime.h>
#include <math.h>

#define S_LEN   16384
#define NCONV   128
#define NBATCH  256
#define TPB     1024   // 16 waves; 2 chunk work-items per wave
#define NGRP    8      // conv groups per row (16 convs, 32 chunks each)
#define DSTRIDE 24
#define BIGQ    (1 << 28)
// LDS layout: sh[0..3]=0 | sh[4+i]=x[i] (i<16384) | sh[16388..16391]=0
// Clamped index (bytes): min(unsigned((4+pos)*4), 65552). pos=-1 -> (0, x[0]).
#define CLMP    65552u

typedef float __attribute__((address_space(1))) as1_float;
typedef float __attribute__((address_space(3))) as3_float;
typedef __attribute__((ext_vector_type(2))) float f2;

// ---------------- setup: per-CHUNK descriptors, LPT fold balancing ----------
__global__ void setup_desc(const int* __restrict__ ks, const int* __restrict__ dil,
                           const int* __restrict__ pad, const float* __restrict__ W,
                           const float* __restrict__ bias, int* __restrict__ ws)
{
  __shared__ int cost_s[NCONV];
  __shared__ int grp_s[NCONV];
  const int ci = threadIdx.x;  // blockDim == 128
  const int is64 = (ks[1] == 0);
  const int k = is64 ? ks[2 * ci]  : ks[ci];
  const int d = is64 ? dil[2 * ci] : dil[ci];
  const int p = is64 ? pad[2 * ci] : pad[ci];
  const int L = S_LEN + 2 * p - d * (k - 1);
  const int A = L / d, B = L - A * d;
  int cost = L * (k + 5) + ((d >= 128) ? (d >> 1) : 64) * (k - 1) * 2;
  if (d == 1) cost = L * (k + 5) * 2;   // scalar path ~2x slots/output
  cost_s[ci] = cost;
  __syncthreads();
  int rank = 0;
  for (int j = 0; j < NCONV; ++j) {
    const int cj = cost_s[j];
    rank += (cj > cost) || (cj == cost && j < ci);
  }
  int gg = rank & 7;
  if ((rank >> 3) & 1) gg = 7 - gg;    // snake-deal convs -> 8 balanced groups
  grp_s[ci] = gg;
  __syncthreads();
  int rho = 0;                         // in-group rank (descending cost)
  for (int j = 0; j < NCONV; ++j) {
    if (grp_s[j] != gg) continue;
    const int cj = cost_s[j];
    rho += (cj > cost) || (cj == cost && j < ci);
  }
  // 2 chunks per conv; fold: chunk j2=2*rho+h -> wave (j2<16 ? j2 : 31-j2).
#pragma unroll
  for (int h = 0; h < 2; ++h) {
    const int j2 = 2 * rho + h;
    const int wv = (j2 < 16) ? j2 : 31 - j2;
    const int sq = (j2 < 16) ? 0 : 1;
    int* dsc = ws + (gg * 32 + wv * 2 + sq) * DSTRIDE;
    dsc[0] = d; dsc[1] = p; dsc[2] = A; dsc[3] = B;
    dsc[4] = ci; dsc[5] = rho; dsc[6] = h; dsc[7] = k;
    ((float*)dsc)[8] = 1.0f / (float)L;
    ((float*)dsc)[9] = bias[ci];
#pragma unroll
    for (int t = 0; t < 11; ++t) ((float*)dsc)[10 + t] = W[ci * 11 + t];
  }
}

// ---------------- helpers ----------------
__device__ __forceinline__ float sgpr_f(float v) {
  return __int_as_float(__builtin_amdgcn_readfirstlane(__float_as_int(v)));
}
__device__ __forceinline__ int sgpr_i(int v) {
  return __builtin_amdgcn_readfirstlane(v);
}
__device__ __forceinline__ float rcpf(float x) { return __builtin_amdgcn_rcpf(x); }

// exact floor(num/d) for small non-negative num; no div sequences
__device__ __forceinline__ int divq(int num, float rd, int d) {
  int q = (int)((float)num * rd);
  q -= (q * d > num);
  q += ((q + 1) * d <= num);
  return q;
}

// byte-indexed clamped reads against the shifted layout
__device__ __forceinline__ f2 rd2b(const float* sh, int ib) {
  unsigned u = (unsigned)ib;
  u = u > CLMP ? CLMP : u;                       // one v_min_u32
  const float* p = (const float*)((const char*)sh + u);
  f2 v; v.x = p[0]; v.y = p[1];                  // fused ds_read2_b32
  return v;
}
__device__ __forceinline__ float ld1b(const float* sh, int ib) {
  unsigned u = (unsigned)ib;
  u = u > CLMP ? CLMP : u;
  return *(const float*)((const char*)sh + u);
}

__device__ __forceinline__ int wcount(bool pred) {   // wave-total, SALU adds
  return (int)__popcll(__ballot(pred));
}

// ---------------- interior pair walk: classes (r0, r0+1), (K-1)-slot window.
// Packed f2 LDS reads, but SCALAR math: VOP3P packed-f32 executes multi-pass
// (~quarter rate) on gfx950; scalar v_fma_f32 is 2cy. The two chains use
// OPPOSITE tap order (x: 0..K-1 ending cur.x; y: cur.y first, then K-2..0)
// so the SLP vectorizer cannot re-pack them into v_pk_fma_f32, while the
// scheduler keeps full freedom (no asm). Window invariant at group top:
// win[j] = taps q0+i+j; step s reads q0+i+W+s, writes slot s.
template <int K>
__device__ __forceinline__ void pwalk(
    const float* sh, const float* wf, const float bval,
    int d, int sb4, int q0, int q1, float& mxA, float& mxB, int& cw)
{
  constexpr int W = K - 1;
  const int n = q1 - q0;
  if (n <= 0) return;
  f2 win[W];
  int bb = (sb4 + q0 * d) * 4;                 // byte index
#pragma unroll
  for (int t = 0; t < W; ++t)
    win[t] = rd2b(sh, bb + t * (d * 4));       // t*(d*4): SALU, hoisted
  bb += W * (d * 4);
  int i = 0;
  for (; i + W <= n; i += W) {
#pragma unroll
    for (int s = 0; s < W; ++s) {
      const f2 cur = rd2b(sh, bb + s * (d * 4));
      float ax = fmaf(wf[0], win[s].x, bval);
      float ay = fmaf(wf[K - 1], cur.y, bval);
#pragma unroll
      for (int t = 1; t < W; ++t)
        ax = fmaf(wf[t], win[(s + t) % W].x, ax);
      ax = fmaf(wf[K - 1], cur.x, ax);
#pragma unroll
      for (int t = W - 1; t >= 1; --t)
        ay = fmaf(wf[t], win[(s + t) % W].y, ay);
      ay = fmaf(wf[0], win[s].y, ay);
      win[s] = cur;
      mxA = fmaxf(mxA, ax);
      mxB = fmaxf(mxB, ay);
      cw += wcount(ax >= 0.f);
      cw += wcount(ay >= 0.f);
    }
    bb += W * (d * 4);
  }
  const int rem = n - i;                       // 0..W-1
  if (rem > 0) {
#pragma unroll
    for (int s = 0; s < W - 1; ++s) {
      const f2 cur = rd2b(sh, bb + s * (d * 4));
      float ax = fmaf(wf[0], win[s].x, bval);
      float ay = fmaf(wf[K - 1], cur.y, bval);
#pragma unroll
      for (int t = 1; t < W; ++t)
        ax = fmaf(wf[t], win[(s + t) % W].x, ax);
      ax = fmaf(wf[K - 1], cur.x, ax);
#pragma unroll
      for (int t = W - 1; t >= 1; --t)
        ay = fmaf(wf[t], win[(s + t) % W].y, ay);
      ay = fmaf(wf[0], win[s].y, ay);
      win[s] = cur;
      const bool ok = (s < rem);
      if (ok) { mxA = fmaxf(mxA, ax); mxB = fmaxf(mxB, ay); }
      cw += wcount(ok && (ax >= 0.f));
      cw += wcount(ok && (ay >= 0.f));
    }
  }
}

// ---------------- scalar rotate walk (d==1 convs, odd-d remainder class),
// (K-1)-slot window form.
template <int K>
__device__ __forceinline__ void swalk(
    const float* sh, const float* wf, float bval,
    int d, int sb4, int q0, int q1, float& mx, int& cw)
{
  constexpr int W = K - 1;
  const int n = q1 - q0;
  if (n <= 0) return;
  float win[W];
  int bb = (sb4 + q0 * d) * 4;
#pragma unroll
  for (int t = 0; t < W; ++t)
    win[t] = ld1b(sh, bb + t * (d * 4));
  bb += W * (d * 4);
  int i = 0;
  for (; i + W <= n; i += W) {
#pragma unroll
    for (int s = 0; s < W; ++s) {
      const float cur = ld1b(sh, bb + s * (d * 4));
      float a = fmaf(wf[0], win[s], bval);
#pragma unroll
      for (int t = 1; t < W; ++t)
        a = fmaf(wf[t], win[(s + t) % W], a);
      a = fmaf(wf[K - 1], cur, a);
      win[s] = cur;
      mx = fmaxf(mx, a);
      cw += wcount(a >= 0.f);
    }
    bb += W * (d * 4);
  }
  const int rem = n - i;
  if (rem > 0) {
#pragma unroll
    for (int s = 0; s < W - 1; ++s) {
      const float cur = ld1b(sh, bb + s * (d * 4));
      float a = fmaf(wf[0], win[s], bval);
#pragma unroll
      for (int t = 1; t < W; ++t)
        a = fmaf(wf[t], win[(s + t) % W], a);
      a = fmaf(wf[K - 1], cur, a);
      win[s] = cur;
      const bool ok = (s < rem);
      if (ok) mx = fmaxf(mx, a);
      cw += wcount(ok && (a >= 0.f));
    }
  }
}

// split class r's q-range [c0,c1) over 64 lanes with mod-32 stagger
template <int K>
__device__ __forceinline__ void scalar_split(
    const float* sh, const float* wf, float bval,
    int d, int p, int r, int c0, int c1, int lane, float& mx, int& cw)
{
  const int n = c1 - c0;
  if (n <= 0) return;
  const int v  = lane;
  const int mm = n >> 6;
  const int sA = (mm >= 32) ? (v & 31) : (((v & 31) * mm) >> 5);
  const int vB = v + 1;
  const int sB = (mm >= 32) ? (vB & 31) : (((vB & 31) * mm) >> 5);
  const int q0 = c0 + (int)(((long long)n * v) >> 6) + sA;
  const int q1 = (v == 63) ? c1 : c0 + (int)(((long long)n * vB) >> 6) + sB;
  swalk<K>(sh, wf, bval, d, r - p + 4, q0, q1, mx, cw);
}

// split pair-column (classes r, r+1) q-range [c0,c1) over 64 lanes
template <int K>
__device__ __forceinline__ void pair_split(
    const float* sh, const float* wf, float bval,
    int d, int p, int r, int c0, int c1, int lane,
    float& mxA, float& mxB, int& cw)
{
  const int n = c1 - c0;
  if (n <= 0) return;
  const int v  = lane;
  const int mm = n >> 6;
  const int sA = (mm >= 32) ? (v & 31) : (((v & 31) * mm) >> 5);
  const int vB = v + 1;
  const int sB = (mm >= 32) ? (vB & 31) : (((vB & 31) * mm) >> 5);
  const int q0 = c0 + (int)(((long long)n * v) >> 6) + sA;
  const int q1 = (v == 63) ? c1 : c0 + (int)(((long long)n * vB) >> 6) + sB;
  pwalk<K>(sh, wf, bval, d, r - p + 4, q0, q1, mxA, mxB, cw);
}

template <int K>
__device__ __forceinline__ void one_out(
    const float* sh, const float* wf, float bval,
    int d, int p, int j, float& mx, int& cw)
{
  float a = bval;
  int bb = (j - p + 4) * 4;
#pragma unroll
  for (int t = 0; t < K; ++t) { a = fmaf(wf[t], ld1b(sh, bb), a); bb += d * 4; }
  mx = fmaxf(mx, a);
  cw += wcount(a >= 0.f);
}

// ---------------- one chunk of one conv ----------------
template <int K>
__device__ __forceinline__ void conv_chunk(
    const float* sh, const float* wf, float bval,
    int d, int p, int A, int B, int h, int lane,
    float& mxA, float& mxB, float& mxs, int& cw)
{
  if (d == 1) {                      // single class (A == L), scalar q-split
    const int H = (A + 1) >> 1;
    scalar_split<K>(sh, wf, bval, 1, p, 0, h ? H : 0, h ? A : H, lane, mxs, cw);
    return;
  }
  const int npair = d >> 1;
  if (d < 4) {                       // d==2/3: single pair column (0,1)
    const int H = (A + 1) >> 1;
    const int Qm = A + (1 < B);
    pair_split<K>(sh, wf, bval, d, p, 0, h ? H : 0, h ? Qm : H,
                  lane, mxA, mxB, cw);
    if (h && lane == 63 && B == 1)
      one_out<K>(sh, wf, bval, d, p, A * d, mxs, cw);
    if (d == 3) {                    // unpaired class r=2
      const int Qr = A + (2 < B);
      scalar_split<K>(sh, wf, bval, d, p, 2, h ? H : 0, h ? Qr : min(H, Qr),
                      lane, mxs, cw);
    }
    return;
  }
  if (npair >= 128) {
    // COLUMN-split: chunk h owns a contiguous half of the pair-columns
    const int half = npair >> 1;
    const int g0 = h ? half : 0;
    const int g1 = h ? npair : half;
    for (int c = g0 + lane; c < g1; c += 64) {
      const int r0 = 2 * c;
      const int Qm = A + (r0 + 1 < B);
      pwalk<K>(sh, wf, bval, d, r0 - p + 4, 0, Qm, mxA, mxB, cw);
      if (B == r0 + 1) one_out<K>(sh, wf, bval, d, p, r0 + A * d, mxs, cw);
    }
  } else if (npair >= 64) {
    // whole columns per lane, q-split [c0,c1)
    const int H = (A + 1) >> 1;
    const int c0 = h ? H : 0;
    const int c1 = h ? BIGQ : H;
    for (int c = lane; c < npair; c += 64) {
      const int r0 = 2 * c;
      const int Qm = A + (r0 + 1 < B);
      pwalk<K>(sh, wf, bval, d, r0 - p + 4, c0, min(c1, Qm), mxA, mxB, cw);
      if (B == r0 + 1 && A >= c0 && A < c1)
        one_out<K>(sh, wf, bval, d, p, r0 + A * d, mxs, cw);
    }
  } else {
    // lane-compose (nv lanes per column), q-split [c0,c1)
    const int H = (A + 1) >> 1;
    const int c0 = h ? H : 0;
    const int c1h = h ? BIGQ : H;
    const float rdp = rcpf((float)npair);
    int v  = (int)((float)lane * rdp);
    int g2 = lane - v * npair;
    if (g2 < 0)           { --v; g2 += npair; }
    else if (g2 >= npair) { ++v; g2 -= npair; }
    const int nv = divq(63 - g2, rdp, npair) + 1;
    const int r0 = 2 * g2;
    const int Qm = A + (r0 + 1 < B);
    const int cc1 = min(c1h, Qm);
    const int n = cc1 - c0;
    if (n > 0) {
      const float rn = rcpf((float)nv);
      const int mm = (int)((float)n * rn);
      const int sA = (mm >= 32) ? (v & 31) : (((v & 31) * mm) >> 5);
      const int vB = v + 1;
      const int sB = (mm >= 32) ? (vB & 31) : (((vB & 31) * mm) >> 5);
      const int q0 = c0 + (int)((float)(n * v) * rn) + sA;   // v==0 -> c0
      const int q1 = (v == nv - 1) ? cc1
                   : c0 + (int)((float)(n * vB) * rn) + sB;
      pwalk<K>(sh, wf, bval, d, r0 - p + 4, q0, q1, mxA, mxB, cw);
    }
    if (v == nv - 1 && B == r0 + 1 && A >= c0 && A < c1h)
      one_out<K>(sh, wf, bval, d, p, r0 + A * d, mxs, cw);
  }
  if ((d & 1) && d > 1) {            // odd d: unpaired last class, q-split
    const int H2 = (A + 1) >> 1;
    const int r = d - 1;
    const int Qr = A + (r < B);
    const int c0 = h ? H2 : 0;
    const int c1 = h ? Qr : min(H2, Qr);
    scalar_split<K>(sh, wf, bval, d, p, r, c0, c1, lane, mxs, cw);
  }
}

// ---------------- hot kernel ----------------
__global__ __launch_bounds__(TPB, 8) void rocket_feats(
    const float* __restrict__ x, const int* __restrict__ ws,
    float* __restrict__ out)
{
  __shared__ float sh[S_LEN + 8];    // shifted layout; 2 blocks/CU
  __shared__ float smx[2][16];
  __shared__ int   scn[2][16];
  __shared__ int   sci[16];
  __shared__ float sin_[16];

  const int tid  = threadIdx.x;
  const int blk  = blockIdx.x;       // blk = b*8 + g: row's blocks adjacent
  const int g    = blk & 7;
  const int b    = blk >> 3;
  const int lane = tid & 63, wid = tid >> 6;   // wid in [0,16)

  const float* xrow = x + (size_t)b * S_LEN;
  {
    const float* gb = xrow + lane * 4;
#pragma unroll
    for (int c = 0; c < 4; ++c) {
      const int off = (wid * 4 + c) * 256;  // floats; dest 16B-aligned (sh+4)
      __builtin_amdgcn_global_load_lds((const as1_float*)(gb + off),
                                       (as3_float*)(sh + 4 + off), 16, 0, 0);
    }
  }
  if (tid < 4) sh[tid] = 0.f;                    // left zero pad
  if (tid >= 4 && tid < 8) sh[S_LEN + tid] = 0.f; // sh[16388..16391] = 0
  __syncthreads();

  for (int sq = 0; sq < 2; ++sq) {
    const int* dsc = ws + (g * 32 + wid * 2 + sq) * DSTRIDE;
    const int d  = sgpr_i(dsc[0]);
    const int p  = sgpr_i(dsc[1]);
    const int A  = sgpr_i(dsc[2]);
    const int B  = sgpr_i(dsc[3]);
    const int ci = sgpr_i(dsc[4]);
    const int t_ = sgpr_i(dsc[5]);
    const int h  = sgpr_i(dsc[6]);
    const int k  = sgpr_i(dsc[7]);
    const float invL = sgpr_f(((const float*)dsc)[8]);
    const float bval = sgpr_f(((const float*)dsc)[9]);
    float wf[11];
#pragma unroll
    for (int t = 0; t < 11; ++t)
      wf[t] = sgpr_f(((const float*)dsc)[10 + t]);

    float mxA = -INFINITY, mxB = -INFINITY, mxs = -INFINITY;
    int cw = 0;                            // wave-total count (uniform/SGPR)

    if (k == 7)
      conv_chunk<7 >(sh, wf, bval, d, p, A, B, h, lane, mxA, mxB, mxs, cw);
    else if (k == 9)
      conv_chunk<9 >(sh, wf, bval, d, p, A, B, h, lane, mxA, mxB, mxs, cw);
    else
      conv_chunk<11>(sh, wf, bval, d, p, A, B, h, lane, mxA, mxB, mxs, cw);

    float mx = fmaxf(fmaxf(mxA, mxB), mxs);
#pragma unroll
    for (int off = 32; off > 0; off >>= 1)
      mx = fmaxf(mx, __shfl_down(mx, off, 64));
    if (lane == 0) {
      smx[h][t_] = mx; scn[h][t_] = cw;
      sci[t_] = ci; sin_[t_] = invL;       // same value from both chunks
    }
  }

  __syncthreads();
  if (tid < 16) {
    const float m = fmaxf(smx[0][tid], smx[1][tid]);
    const int   c = scn[0][tid] + scn[1][tid];
    out[(size_t)b * (2 * NCONV) + 2 * sci[tid]]     = m;
    out[(size_t)b * (2 * NCONV) + 2 * sci[tid] + 1] = (float)c * sin_[tid];
  }
}

extern "C" void kernel_launch(void* const* d_in, const int* in_sizes, int n_in,
                              void* d_out, int out_size, void* d_ws, size_t ws_size,
                              hipStream_t stream) {
  const float* x    = (const float*)d_in[0];
  const float* W    = (const float*)d_in[1];
  const float* bias = (const float*)d_in[2];
  const int*   ks   = (const int*)d_in[3];
  const int*   dil  = (const int*)d_in[4];
  const int*   pad  = (const int*)d_in[5];
  float* out = (float*)d_out;
  int*   ws  = (int*)d_ws;  // 8*32*24*4 = 24576 bytes

  hipLaunchKernelGGL(setup_desc, dim3(1), dim3(NCONV), 0, stream,
                     ks, dil, pad, W, bias, ws);
  hipLaunchKernelGGL(rocket_feats, dim3(NBATCH * NGRP), dim3(TPB), 0, stream,
                     x, ws, out);
}

// Round 7
// 283.249 us; speedup vs baseline: 1.2334x; 1.2334x over previous
//
#include <hip/hip_runtime.h>
#include <math.h>

#define S_LEN   16384
#define NCONV   128
#define NBATCH  256
#define TPB     512    // 8 waves; 4 chunk work-items per wave
#define NGRP    8      // conv groups per row (16 convs, 32 chunks each)
#define DSTRIDE 24
#define BIGQ    (1 << 28)
// LDS layout: sh[0..3]=0 | sh[4+i]=x[i] (i<16384) | sh[16388..16389]=0
// Clamped index (bytes): min(unsigned((4+pos)*4), 65552). pos=-1 -> (0, x[0]).
#define CLMP    65552u

typedef float __attribute__((address_space(1))) as1_float;
typedef float __attribute__((address_space(3))) as3_float;
typedef __attribute__((ext_vector_type(2))) float f2;
typedef unsigned long long u64;

// ---------------- setup: per-CHUNK descriptors, LPT fold balancing ----------
__global__ void setup_desc(const int* __restrict__ ks, const int* __restrict__ dil,
                           const int* __restrict__ pad, const float* __restrict__ W,
                           const float* __restrict__ bias, int* __restrict__ ws)
{
  __shared__ int cost_s[NCONV];
  __shared__ int grp_s[NCONV];
  const int ci = threadIdx.x;  // blockDim == 128
  const int is64 = (ks[1] == 0);
  const int k = is64 ? ks[2 * ci]  : ks[ci];
  const int d = is64 ? dil[2 * ci] : dil[ci];
  const int p = is64 ? pad[2 * ci] : pad[ci];
  const int L = S_LEN + 2 * p - d * (k - 1);
  const int A = L / d, B = L - A * d;
  int cost = L * (k + 5) + ((d >= 128) ? (d >> 1) : 64) * (k - 1) * 2;
  if (d == 1) cost = L * (k + 5) * 2;   // scalar path ~2x slots/output
  cost_s[ci] = cost;
  __syncthreads();
  int rank = 0;
  for (int j = 0; j < NCONV; ++j) {
    const int cj = cost_s[j];
    rank += (cj > cost) || (cj == cost && j < ci);
  }
  int gg = rank & 7;
  if ((rank >> 3) & 1) gg = 7 - gg;    // snake-deal convs -> 8 balanced groups
  grp_s[ci] = gg;
  __syncthreads();
  int rho = 0;                         // in-group rank (descending cost)
  for (int j = 0; j < NCONV; ++j) {
    if (grp_s[j] != gg) continue;
    const int cj = cost_s[j];
    rho += (cj > cost) || (cj == cost && j < ci);
  }
  // 2 chunks per conv; snake-fold 32 chunks onto 8 waves x 4 slots:
  // j2 = 2*rho+h; round r=j2>>3; pos=j2&7; wave = r odd ? 7-pos : pos; sq = r.
  // Wave w gets cost-ranks {w, 15-w, 16+w, 31-w} -> near-constant sum (LPT).
#pragma unroll
  for (int h = 0; h < 2; ++h) {
    const int j2 = 2 * rho + h;
    const int r  = j2 >> 3;
    const int pos = j2 & 7;
    const int wv = (r & 1) ? (7 - pos) : pos;
    int* dsc = ws + (gg * 32 + wv * 4 + r) * DSTRIDE;
    dsc[0] = d; dsc[1] = p; dsc[2] = A; dsc[3] = B;
    dsc[4] = ci; dsc[5] = rho; dsc[6] = h; dsc[7] = k;
    ((float*)dsc)[8] = 1.0f / (float)L;
    ((float*)dsc)[9] = bias[ci];
#pragma unroll
    for (int t = 0; t < 11; ++t) ((float*)dsc)[10 + t] = W[ci * 11 + t];
  }
}

// ---------------- helpers ----------------
__device__ __forceinline__ float sgpr_f(float v) {
  return __int_as_float(__builtin_amdgcn_readfirstlane(__float_as_int(v)));
}
__device__ __forceinline__ int sgpr_i(int v) {
  return __builtin_amdgcn_readfirstlane(v);
}
__device__ __forceinline__ float rcpf(float x) { return __builtin_amdgcn_rcpf(x); }

// exact floor(num/d) for small non-negative num; no div sequences
__device__ __forceinline__ int divq(int num, float rd, int d) {
  int q = (int)((float)num * rd);
  q -= (q * d > num);
  q += ((q + 1) * d <= num);
  return q;
}

// byte-indexed clamped reads against the shifted layout
__device__ __forceinline__ f2 rd2b(const float* sh, int ib) {
  unsigned u = (unsigned)ib;
  u = u > CLMP ? CLMP : u;                       // one v_min_u32
  const float* p = (const float*)((const char*)sh + u);
  f2 v; v.x = p[0]; v.y = p[1];                  // fused ds_read2_b32
  return v;
}
__device__ __forceinline__ float ld1b(const float* sh, int ib) {
  unsigned u = (unsigned)ib;
  u = u > CLMP ? CLMP : u;
  return *(const float*)((const char*)sh + u);
}

__device__ __forceinline__ f2 pfma(f2 a, f2 b, f2 c) {
#if __has_builtin(__builtin_elementwise_fma)
  return __builtin_elementwise_fma(a, b, c);
#else
  f2 r; r.x = fmaf(a.x, b.x, c.x); r.y = fmaf(a.y, b.y, c.y); return r;
#endif
}
__device__ __forceinline__ f2 pmax(f2 a, f2 b) {
#if __has_builtin(__builtin_elementwise_max)
  return __builtin_elementwise_max(a, b);
#else
  f2 r; r.x = fmaxf(a.x, b.x); r.y = fmaxf(a.y, b.y); return r;
#endif
}
__device__ __forceinline__ int wcount(bool pred) {   // wave-total, SALU adds
  return (int)__popcll(__ballot(pred));
}

// ---------------- interior pair walk: classes (r0, r0+1), all reads clamped
// (correct everywhere incl. pos=-1 via shifted layout), weights as SGPR-pair
// u64, bias folded into tap-0 pfma, SALU-hoisted s*d addressing, ballot cnt.
// At the 128-VGPR cap (TPB=512, bounds(512,4)) the compiler can hoist the
// whole unrolled group's K independent ds_read2s ahead of the FMA chains.
template <int K>
__device__ __forceinline__ void pwalk(
    const float* sh, const u64* wu, const f2 bbv,
    int d, int sb4, int q0, int q1, f2& mxv, int& cw)
{
  const int n = q1 - q0;
  if (n <= 0) return;
  f2 win[K];
  int bb = (sb4 + q0 * d) * 4;                 // byte index
#pragma unroll
  for (int t = 0; t < K - 1; ++t)
    win[t] = rd2b(sh, bb + t * (d * 4));       // t*(d*4): SALU, hoisted
  bb += (K - 1) * (d * 4);
  int i = 0;
  for (; i + K <= n; i += K) {
#pragma unroll
    for (int s = 0; s < K; ++s) {
      const f2 cur = rd2b(sh, bb + s * (d * 4));
      f2 a = pfma(__builtin_bit_cast(f2, wu[0]), win[s % K], bbv);
#pragma unroll
      for (int t = 1; t < K; ++t)
        a = pfma(__builtin_bit_cast(f2, wu[t]),
                 (t == K - 1) ? cur : win[(s + t) % K], a);
      win[(s + K - 1) % K] = cur;
      mxv = pmax(mxv, a);
      cw += wcount(a.x >= 0.f);
      cw += wcount(a.y >= 0.f);
    }
    bb += K * (d * 4);
  }
  const int rem = n - i;
  if (rem > 0) {
#pragma unroll
    for (int s = 0; s < K - 1; ++s) {
      const f2 cur = rd2b(sh, bb + s * (d * 4));
      f2 a = pfma(__builtin_bit_cast(f2, wu[0]), win[s % K], bbv);
#pragma unroll
      for (int t = 1; t < K; ++t)
        a = pfma(__builtin_bit_cast(f2, wu[t]),
                 (t == K - 1) ? cur : win[(s + t) % K], a);
      win[(s + K - 1) % K] = cur;
      const bool ok = (s < rem);
      if (ok) mxv = pmax(mxv, a);
      cw += wcount(ok && (a.x >= 0.f));
      cw += wcount(ok && (a.y >= 0.f));
    }
  }
}

// ---------------- scalar rotate walk (d==1 convs, odd-d remainder class) ----
template <int K>
__device__ __forceinline__ void swalk(
    const float* sh, const float* w, float bval,
    int d, int sb4, int q0, int q1, float& mx, int& cw)
{
  const int n = q1 - q0;
  if (n <= 0) return;
  float win[K];
  int bb = (sb4 + q0 * d) * 4;
#pragma unroll
  for (int t = 0; t < K - 1; ++t)
    win[t] = ld1b(sh, bb + t * (d * 4));
  bb += (K - 1) * (d * 4);
  int i = 0;
  for (; i + K <= n; i += K) {
#pragma unroll
    for (int s = 0; s < K; ++s) {
      const float cur = ld1b(sh, bb + s * (d * 4));
      float a = fmaf(w[0], win[s % K], bval);
#pragma unroll
      for (int t = 1; t < K; ++t)
        a = fmaf(w[t], (t == K - 1) ? cur : win[(s + t) % K], a);
      win[(s + K - 1) % K] = cur;
      mx = fmaxf(mx, a);
      cw += wcount(a >= 0.f);
    }
    bb += K * (d * 4);
  }
  const int rem = n - i;
  if (rem > 0) {
#pragma unroll
    for (int s = 0; s < K - 1; ++s) {
      const float cur = ld1b(sh, bb + s * (d * 4));
      float a = fmaf(w[0], win[s % K], bval);
#pragma unroll
      for (int t = 1; t < K; ++t)
        a = fmaf(w[t], (t == K - 1) ? cur : win[(s + t) % K], a);
      win[(s + K - 1) % K] = cur;
      const bool ok = (s < rem);
      if (ok) mx = fmaxf(mx, a);
      cw += wcount(ok && (a >= 0.f));
    }
  }
}

// split class r's q-range [c0,c1) over 64 lanes with mod-32 stagger
template <int K>
__device__ __forceinline__ void scalar_split(
    const float* sh, const float* w, float bval,
    int d, int p, int r, int c0, int c1, int lane, float& mx, int& cw)
{
  const int n = c1 - c0;
  if (n <= 0) return;
  const int v  = lane;
  const int mm = n >> 6;
  const int sA = (mm >= 32) ? (v & 31) : (((v & 31) * mm) >> 5);
  const int vB = v + 1;
  const int sB = (mm >= 32) ? (vB & 31) : (((vB & 31) * mm) >> 5);
  const int q0 = c0 + (int)(((long long)n * v) >> 6) + sA;
  const int q1 = (v == 63) ? c1 : c0 + (int)(((long long)n * vB) >> 6) + sB;
  swalk<K>(sh, w, bval, d, r - p + 4, q0, q1, mx, cw);
}

template <int K>
__device__ __forceinline__ void one_out(
    const float* sh, const float* w, float bval,
    int d, int p, int j, float& mx, int& cw)
{
  float a = bval;
  int bb = (j - p + 4) * 4;
#pragma unroll
  for (int t = 0; t < K; ++t) { a = fmaf(w[t], ld1b(sh, bb), a); bb += d * 4; }
  mx = fmaxf(mx, a);
  cw += wcount(a >= 0.f);
}

// ---------------- one chunk of one conv ----------------
template <int K>
__device__ __forceinline__ void conv_chunk(
    const float* sh, const u64* wu, const float* w, float bval, const f2 bbv,
    int d, int p, int A, int B, int h, int lane,
    f2& mxv, float& mxs, int& cw)
{
  if (d == 1) {                      // single class (A == L), scalar q-split
    const int H = (A + 1) >> 1;
    scalar_split<K>(sh, w, bval, 1, p, 0, h ? H : 0, h ? A : H, lane, mxs, cw);
    return;
  }
  const int npair = d >> 1;
  if (npair >= 128) {
    // COLUMN-split: chunk h owns a contiguous half of the pair-columns
    const int half = npair >> 1;
    const int g0 = h ? half : 0;
    const int g1 = h ? npair : half;
    for (int c = g0 + lane; c < g1; c += 64) {
      const int r0 = 2 * c;
      const int Qm = A + (r0 + 1 < B);
      pwalk<K>(sh, wu, bbv, d, r0 - p + 4, 0, Qm, mxv, cw);
      if (B == r0 + 1) one_out<K>(sh, w, bval, d, p, r0 + A * d, mxs, cw);
    }
  } else if (npair >= 64) {
    // whole columns per lane, q-split [c0,c1)
    const int H = (A + 1) >> 1;
    const int c0 = h ? H : 0;
    const int c1 = h ? BIGQ : H;
    for (int c = lane; c < npair; c += 64) {
      const int r0 = 2 * c;
      const int Qm = A + (r0 + 1 < B);
      pwalk<K>(sh, wu, bbv, d, r0 - p + 4, c0, min(c1, Qm), mxv, cw);
      if (B == r0 + 1 && A >= c0 && A < c1)
        one_out<K>(sh, w, bval, d, p, r0 + A * d, mxs, cw);
    }
  } else {
    // lane-compose (nv lanes per column), q-split [c0,c1)
    const int H = (A + 1) >> 1;
    const int c0 = h ? H : 0;
    const int c1h = h ? BIGQ : H;
    const float rdp = rcpf((float)npair);
    int v  = (int)((float)lane * rdp);
    int g2 = lane - v * npair;
    if (g2 < 0)           { --v; g2 += npair; }
    else if (g2 >= npair) { ++v; g2 -= npair; }
    const int nv = divq(63 - g2, rdp, npair) + 1;
    const int r0 = 2 * g2;
    const int Qm = A + (r0 + 1 < B);
    const int cc1 = min(c1h, Qm);
    const int n = cc1 - c0;
    if (n > 0) {
      const float rn = rcpf((float)nv);
      const int mm = (int)((float)n * rn);
      const int sA = (mm >= 32) ? (v & 31) : (((v & 31) * mm) >> 5);
      const int vB = v + 1;
      const int sB = (mm >= 32) ? (vB & 31) : (((vB & 31) * mm) >> 5);
      const int q0 = c0 + (int)((float)(n * v) * rn) + sA;   // v==0 -> c0
      const int q1 = (v == nv - 1) ? cc1
                   : c0 + (int)((float)(n * vB) * rn) + sB;
      pwalk<K>(sh, wu, bbv, d, r0 - p + 4, q0, q1, mxv, cw);
    }
    if (v == nv - 1 && B == r0 + 1 && A >= c0 && A < c1h)
      one_out<K>(sh, w, bval, d, p, r0 + A * d, mxs, cw);
  }
  if ((d & 1) && d > 1) {            // odd d: unpaired last class, q-split
    const int H2 = (A + 1) >> 1;
    const int r = d - 1;
    const int Qr = A + (r < B);
    const int c0 = h ? H2 : 0;
    const int c1 = h ? Qr : min(H2, Qr);
    scalar_split<K>(sh, w, bval, d, p, r, c0, c1, lane, mxs, cw);
  }
}

// ---------------- hot kernel ----------------
__global__ __launch_bounds__(TPB, 4) void rocket_feats(
    const float* __restrict__ x, const int* __restrict__ ws,
    float* __restrict__ out)
{
  __shared__ float sh[S_LEN + 8];    // shifted layout; 2 blocks/CU (LDS-lim)
  __shared__ float smx[2][16];
  __shared__ int   scn[2][16];
  __shared__ int   sci[16];
  __shared__ float sin_[16];

  const int tid  = threadIdx.x;
  const int blk  = blockIdx.x;       // blk = b*8 + g: row's blocks adjacent
  const int g    = blk & 7;
  const int b    = blk >> 3;
  const int lane = tid & 63, wid = tid >> 6;   // wid in [0,8)

  const float* xrow = x + (size_t)b * S_LEN;
  {
    const float* gb = xrow + lane * 4;
#pragma unroll
    for (int c = 0; c < 8; ++c) {
      const int off = (wid * 8 + c) * 256;  // floats; dest 16B-aligned (sh+4)
      __builtin_amdgcn_global_load_lds((const as1_float*)(gb + off),
                                       (as3_float*)(sh + 4 + off), 16, 0, 0);
    }
  }
  if (tid < 4) sh[tid] = 0.f;                    // left zero pad
  if (tid >= 4 && tid < 8) sh[S_LEN + tid] = 0.f; // sh[16388..16391] = 0
  __syncthreads();

  for (int sq = 0; sq < 4; ++sq) {
    const int* dsc = ws + (g * 32 + wid * 4 + sq) * DSTRIDE;
    const int d  = sgpr_i(dsc[0]);
    const int p  = sgpr_i(dsc[1]);
    const int A  = sgpr_i(dsc[2]);
    const int B  = sgpr_i(dsc[3]);
    const int ci = sgpr_i(dsc[4]);
    const int t_ = sgpr_i(dsc[5]);
    const int h  = sgpr_i(dsc[6]);
    const int k  = sgpr_i(dsc[7]);
    const float invL = sgpr_f(((const float*)dsc)[8]);
    const float bval = sgpr_f(((const float*)dsc)[9]);
    float wf[11]; u64 wu[11];
#pragma unroll
    for (int t = 0; t < 11; ++t) {
      wf[t] = sgpr_f(((const float*)dsc)[10 + t]);
      const unsigned wb = (unsigned)__float_as_int(wf[t]);
      wu[t] = ((u64)wb << 32) | (u64)wb;   // wave-uniform -> SGPR pair
    }
    f2 bbv; bbv.x = bval; bbv.y = bval;    // persistent VGPR pair (c-operand)

    f2 mxv; mxv.x = -INFINITY; mxv.y = -INFINITY;
    float mxs = -INFINITY;
    int cw = 0;                            // wave-total count (uniform/SGPR)

    if (k == 7)
      conv_chunk<7 >(sh, wu, wf, bval, bbv, d, p, A, B, h, lane, mxv, mxs, cw);
    else if (k == 9)
      conv_chunk<9 >(sh, wu, wf, bval, bbv, d, p, A, B, h, lane, mxv, mxs, cw);
    else
      conv_chunk<11>(sh, wu, wf, bval, bbv, d, p, A, B, h, lane, mxv, mxs, cw);

    float mx = fmaxf(fmaxf(mxv.x, mxv.y), mxs);
#pragma unroll
    for (int off = 32; off > 0; off >>= 1)
      mx = fmaxf(mx, __shfl_down(mx, off, 64));
    if (lane == 0) {
      smx[h][t_] = mx; scn[h][t_] = cw;
      sci[t_] = ci; sin_[t_] = invL;       // same value from both chunks
    }
  }

  __syncthreads();
  if (tid < 16) {
    const float m = fmaxf(smx[0][tid], smx[1][tid]);
    const int   c = scn[0][tid] + scn[1][tid];
    out[(size_t)b * (2 * NCONV) + 2 * sci[tid]]     = m;
    out[(size_t)b * (2 * NCONV) + 2 * sci[tid] + 1] = (float)c * sin_[tid];
  }
}

extern "C" void kernel_launch(void* const* d_in, const int* in_sizes, int n_in,
                              void* d_out, int out_size, void* d_ws, size_t ws_size,
                              hipStream_t stream) {
  const float* x    = (const float*)d_in[0];
  const float* W    = (const float*)d_in[1];
  const float* bias = (const float*)d_in[2];
  const int*   ks   = (const int*)d_in[3];
  const int*   dil  = (const int*)d_in[4];
  const int*   pad  = (const int*)d_in[5];
  float* out = (float*)d_out;
  int*   ws  = (int*)d_ws;  // 8*32*24*4 = 24576 bytes

  hipLaunchKernelGGL(setup_desc, dim3(1), dim3(NCONV), 0, stream,
                     ks, dil, pad, W, bias, ws);
  hipLaunchKernelGGL(rocket_feats, dim3(NBATCH * NGRP), dim3(TPB), 0, stream,
                     x, ws, out);
}